// Round 12
// baseline (134.636 us; speedup 1.0000x reference)
//
#include <hip/hip_runtime.h>
#include <hip/hip_bf16.h>
#include <hip/hip_fp16.h>
#include <math.h>

// DCNv2 forward, fully fused, f16 pipeline: per block stage an 8x20-pixel NHWC
// f16 window in LDS (XOR-swizzled, 128 B/pixel); aux conv (f16 MFMA) reads
// taps from it -> oml in LDS; deformable bilinear runs on PACKED f16
// (v_pk_fma_f16) straight into MFMA A-fragments (D = V*W^T); rare exec-masked
// global fallback for large offsets. Tile = 4 rows x 16 cols, 4 waves (one
// per row), ~24.8 KB LDS -> 6 blocks/CU.
// x [4,64,192,192] f32; w_off [18,64,3,3]; b_off[18]; w_mod [9,64,3,3]; b_mod[9];
// w [64,64,3,3]; b[64]; out [4,64,192,192] f32.

#define NB   4
#define CIN  64
#define COUT 64
#define HH   192
#define WW   192
#define HW   (HH*WW)

typedef __attribute__((ext_vector_type(4))) float f32x4;
typedef __attribute__((ext_vector_type(8))) _Float16 f16x8;
typedef __attribute__((ext_vector_type(4))) unsigned int u32x4;

__device__ __forceinline__ int iclamp(int v, int lo, int hi) {
    return v < lo ? lo : (v > hi ? hi : v);
}
__device__ __forceinline__ unsigned short f16bits(float f) {
    __half h = __float2half(f);
    union { __half h; unsigned short u; } t; t.h = h; return t.u;
}
__device__ __forceinline__ float h2f(unsigned short u) {
    union { unsigned short u; __half h; } t; t.u = u; return __half2float(t.h);
}

// ---------------------------------------------------------------------------
// Kernel A: x f32 NCHW -> xt f16 NHWC (128 B per pixel).
// ---------------------------------------------------------------------------
__global__ __launch_bounds__(256) void to_nhwc(
        const float* __restrict__ x, unsigned short* __restrict__ xt) {
    int n  = blockIdx.y;
    int px = blockIdx.x * 256 + threadIdx.x;     // 0..HW-1
    const float* xn = x + (size_t)n * CIN * HW + px;
    union { unsigned short us[64]; u32x4 q[8]; } pk;
#pragma unroll
    for (int c = 0; c < 64; c++) pk.us[c] = f16bits(xn[c * HW]);
    u32x4* dst = (u32x4*)(xt + ((size_t)n * HW + px) * 64);
#pragma unroll
    for (int i = 0; i < 8; i++) dst[i] = pk.q[i];
}

// ---------------------------------------------------------------------------
// Kernel 0: weight repack into MFMA fragment order (f16 bits).
//  wfrag (main): idx = (((k*4+nf)*2+kc)*64 + l)*8 + j
//        holds W[o = nf*16 + (l&15)][c = kc*32 + (l>>4)*8 + j]
//  wauxf (aux, 32 out-ch padded from 27): idx = ((k*4 + ga*2 + kc)*64 + l)*8 + j
//  baux  f32[32]: b_off | b_mod | 0
// ---------------------------------------------------------------------------
__global__ __launch_bounds__(256) void prep_weights(
        const float* __restrict__ w, const float* __restrict__ w_off,
        const float* __restrict__ w_mod, const float* __restrict__ b_off,
        const float* __restrict__ b_mod, unsigned short* __restrict__ wfrag,
        unsigned short* __restrict__ wauxf, float* __restrict__ baux) {
    int idx = blockIdx.x * 256 + threadIdx.x;
    if (idx < 36864) {
        int j    = idx & 7;
        int lane = (idx >> 3) & 63;
        int kc   = (idx >> 9) & 1;
        int g    = (idx >> 10) & 3;
        int k    = idx >> 12;
        int o = g * 16 + (lane & 15);
        int c = kc * 32 + (lane >> 4) * 8 + j;
        wfrag[idx] = f16bits(w[(o * 64 + c) * 9 + k]);
    }
    if (idx < 18432) {
        int j    = idx & 7;
        int lane = (idx >> 3) & 63;
        int kc   = (idx >> 9) & 1;
        int ga   = (idx >> 10) & 1;
        int k    = idx >> 11;
        int o = ga * 16 + (lane & 15);
        int c = kc * 32 + (lane >> 4) * 8 + j;
        float v = 0.f;
        if (o < 18)      v = w_off[(o * 64 + c) * 9 + k];
        else if (o < 27) v = w_mod[((o - 18) * 64 + c) * 9 + k];
        wauxf[idx] = f16bits(v);
    }
    if (idx < 32) {
        float v = 0.f;
        if (idx < 18)      v = b_off[idx];
        else if (idx < 27) v = b_mod[idx - 18];
        baux[idx] = v;
    }
}

// ---------------------------------------------------------------------------
// Fused kernel. Tile = 4 output rows x 16 cols; wave wv = row r4.
// Window: 8 rows x 20 cols (rows ho4-2..ho4+5, cols wobase-2..wobase+17),
// 128 B/slot, XOR-swizzled (byte ^ (slot&7)<<4). 24.8 KB LDS.
// ---------------------------------------------------------------------------
__global__ __launch_bounds__(256, 6) void dcn_fused(
        const unsigned short* __restrict__ xt,
        const unsigned short* __restrict__ wfrag,
        const unsigned short* __restrict__ wauxf,
        const float* __restrict__ baux,
        const float* __restrict__ bias,
        float* __restrict__ out) {
    __shared__ __align__(16) unsigned short win[160 * 64];  // 20480 B
    __shared__ unsigned short oml[4][32][17];               // 4352 B (f16)

    int tid = threadIdx.x;
    int l   = tid & 63;
    int r4  = __builtin_amdgcn_readfirstlane(tid >> 6);   // 0..3 = output row

    int id = blockIdx.x;                        // 0..2303
    int sw = (id & 7) * 288 + (id >> 3);        // bijective XCD swizzle
    int n  = sw / 576;
    int r  = sw % 576;
    int ho4    = (r / 12) * 4;                  // 48 row-tiles
    int wobase = (r % 12) * 16;                 // 12 col-tiles

    const char* xb = (const char*)xt + (size_t)n * HW * 128;

    // ------- stage the 8x20 window into LDS (coalesced, swizzled) -------
    // 160 slots x 8 16B-parts = 1280 units; 5 passes of 256 threads.
    {
        int part = tid & 7;                     // 16B part within pixel line
#pragma unroll
        for (int pass = 0; pass < 5; pass++) {
            int slot = (pass * 256 + tid) >> 3; // 0..159
            int rw = slot / 20, cl = slot - rw * 20;
            int gy = iclamp(ho4 - 2 + rw, 0, HH - 1);
            int gx = iclamp(wobase - 2 + cl, 0, WW - 1);
            u32x4 v = *(const u32x4*)(xb + ((size_t)gy * WW + gx) * 128 + part * 16);
            *(u32x4*)((char*)win + slot * 128 + ((part * 16) ^ ((slot & 7) << 4))) = v;
        }
    }
    __syncthreads();

    // ================= Phase A: aux conv for this wave's row =================
    {
        f32x4 aacc[2];
        aacc[0] = (f32x4){0.f, 0.f, 0.f, 0.f};
        aacc[1] = (f32x4){0.f, 0.f, 0.f, 0.f};
        const f16x8 zero8 = (f16x8){0, 0, 0, 0, 0, 0, 0, 0};
        int pa   = l & 15;                      // px in row, 0..15
        int cba  = (l >> 4) * 16;               // 8-ch chunk byte offset
        int ho_w = ho4 + r4;

#pragma unroll 1
        for (int k = 0; k < 9; k++) {
            int ky = k / 3, kx = k - 3 * (k / 3);
            int ys = ho_w + ky - 1;
            if ((unsigned)ys >= (unsigned)HH) continue;   // uniform row skip
            int xs = wobase + pa + kx - 1;
            bool ok = (unsigned)xs < (unsigned)WW;
            int sA = (r4 + ky + 1) * 20 + (pa + kx + 1);  // window slot
            const char* pp = (const char*)win + sA * 128;
            int xw = (sA & 7) << 4;
            const f16x8* wa = ((const f16x8*)wauxf) + (k * 4) * 64 + l;
#pragma unroll
            for (int kc = 0; kc < 2; kc++) {
                f16x8 bv = *(const f16x8*)(pp + ((kc * 64 + cba) ^ xw));
                if (!ok) bv = zero8;
                f16x8 a0 = wa[(kc)     * 64];      // o 0..15
                f16x8 a1 = wa[(2 + kc) * 64];      // o 16..31
                aacc[0] = __builtin_amdgcn_mfma_f32_16x16x32_f16(a0, bv, aacc[0], 0, 0, 0);
                aacc[1] = __builtin_amdgcn_mfma_f32_16x16x32_f16(a1, bv, aacc[1], 0, 0, 0);
            }
        }
#pragma unroll
        for (int h = 0; h < 2; h++) {
#pragma unroll
            for (int rr = 0; rr < 4; rr++) {
                int o = h * 16 + (l >> 4) * 4 + rr;
                float v = aacc[h][rr] + baux[o];
                if (o >= 18) v = 2.f / (1.f + expf(-v));
                oml[r4][o][pa] = f16bits(v);
            }
        }
    }
    __syncthreads();   // window + oml ready; no further barriers

    // ================= Phase B: deform sample + main conv =================
    f32x4 acc[4];
#pragma unroll
    for (int nf = 0; nf < 4; nf++) acc[nf] = (f32x4){0.f, 0.f, 0.f, 0.f};

    int p_loc = l & 15;             // pixel within wave's 16 (M-row)
    int chunk = l >> 4;             // K-chunk 0..3
    int ho_w  = ho4 + r4;
    int wox   = wobase + p_loc;     // global wo of this pixel
    int cb0   = chunk * 16;         // chunk byte offset within pixel line

    union Q { u32x4 u; __half2 h2[4]; };

#pragma unroll 1
    for (int k = 0; k < 9; k++) {
        // weight B-fragments (L1-broadcast across waves) — issue early
        const f16x8* wfk = ((const f16x8*)wfrag) + (k * 8) * 64 + l;
        f16x8 wB[8];
#pragma unroll
        for (int f = 0; f < 8; f++) wB[f] = wfk[f * 64];

        // --- geometry ---
        int ky = k / 3, kx = k - 3 * (k / 3);
        float offy = h2f(oml[r4][2 * k][p_loc]);
        float offx = h2f(oml[r4][2 * k + 1][p_loc]);
        float mm   = h2f(oml[r4][18 + k][p_loc]);
        float py  = offy + (float)(ho_w - 1 + ky);
        float pxf = offx + (float)(wox - 1 + kx);
        float y0f = floorf(py), x0f = floorf(pxf);
        float ly = py - y0f, lx = pxf - x0f;
        int y0 = (int)y0f, x0 = (int)x0f;
        int y1 = y0 + 1, x1 = x0 + 1;
        bool y0ok = (unsigned)y0 < (unsigned)HH, y1ok = (unsigned)y1 < (unsigned)HH;
        bool x0ok = (unsigned)x0 < (unsigned)WW, x1ok = (unsigned)x1 < (unsigned)WW;
        float wt0 = (y0ok && x0ok) ? mm * (1.f - ly) * (1.f - lx) : 0.f;
        float wt1 = (y0ok && x1ok) ? mm * (1.f - ly) * lx         : 0.f;
        float wt2 = (y1ok && x0ok) ? mm * ly * (1.f - lx)         : 0.f;
        float wt3 = (y1ok && x1ok) ? mm * ly * lx                 : 0.f;
        int y0c = iclamp(y0, 0, HH - 1), y1c = iclamp(y1, 0, HH - 1);
        int x0c = iclamp(x0, 0, WW - 1), x1c = iclamp(x1, 0, WW - 1);

        // --- window slots ---
        int sy0 = y0c - ho4 + 2,    sy1 = y1c - ho4 + 2;     // want 0..7
        int sx0 = x0c - wobase + 2, sx1 = x1c - wobase + 2;  // want 0..19
        int sy0c = iclamp(sy0, 0, 7),  sy1c = iclamp(sy1, 0, 7);
        int sx0c = iclamp(sx0, 0, 19), sx1c = iclamp(sx1, 0, 19);
        bool fb00 = (wt0 > 0.f) && ((sy0 != sy0c) | (sx0 != sx0c));
        bool fb01 = (wt1 > 0.f) && ((sy0 != sy0c) | (sx1 != sx1c));
        bool fb10 = (wt2 > 0.f) && ((sy1 != sy1c) | (sx0 != sx0c));
        bool fb11 = (wt3 > 0.f) && ((sy1 != sy1c) | (sx1 != sx1c));

        int s00 = sy0c * 20 + sx0c, s01 = sy0c * 20 + sx1c;
        int s10 = sy1c * 20 + sx0c, s11 = sy1c * 20 + sx1c;
        const char* w00 = (const char*)win + s00 * 128;
        const char* w01 = (const char*)win + s01 * 128;
        const char* w10 = (const char*)win + s10 * 128;
        const char* w11 = (const char*)win + s11 * 128;
        int x00 = (s00 & 7) << 4, x01 = (s01 & 7) << 4;
        int x10 = (s10 & 7) << 4, x11 = (s11 & 7) << 4;
        Q q0, q1, q2, q3, q4, q5, q6, q7;
        q0.u = *(const u32x4*)(w00 + ((cb0)      ^ x00));
        q1.u = *(const u32x4*)(w00 + ((cb0 + 64) ^ x00));
        q2.u = *(const u32x4*)(w01 + ((cb0)      ^ x01));
        q3.u = *(const u32x4*)(w01 + ((cb0 + 64) ^ x01));
        q4.u = *(const u32x4*)(w10 + ((cb0)      ^ x10));
        q5.u = *(const u32x4*)(w10 + ((cb0 + 64) ^ x10));
        q6.u = *(const u32x4*)(w11 + ((cb0)      ^ x11));
        q7.u = *(const u32x4*)(w11 + ((cb0 + 64) ^ x11));

        // --- rare fallback: nonzero-weight corner outside window ---
        if (__builtin_expect(fb00 | fb01 | fb10 | fb11, 0)) {
            if (fb00) { const char* gp = xb + ((size_t)y0c * WW + x0c) * 128 + cb0;
                        q0.u = *(const u32x4*)gp; q1.u = *(const u32x4*)(gp + 64); }
            if (fb01) { const char* gp = xb + ((size_t)y0c * WW + x1c) * 128 + cb0;
                        q2.u = *(const u32x4*)gp; q3.u = *(const u32x4*)(gp + 64); }
            if (fb10) { const char* gp = xb + ((size_t)y1c * WW + x0c) * 128 + cb0;
                        q4.u = *(const u32x4*)gp; q5.u = *(const u32x4*)(gp + 64); }
            if (fb11) { const char* gp = xb + ((size_t)y1c * WW + x1c) * 128 + cb0;
                        q6.u = *(const u32x4*)gp; q7.u = *(const u32x4*)(gp + 64); }
        }

        // --- packed f16 bilinear -> A-fragments (v_pk_fma_f16, no repack) ---
        __half2 wv0 = __float2half2_rn(wt0);
        __half2 wv1 = __float2half2_rn(wt1);
        __half2 wv2 = __float2half2_rn(wt2);
        __half2 wv3 = __float2half2_rn(wt3);
        union { __half2 h2[4]; f16x8 v; } fA0, fA1;
#pragma unroll
        for (int j = 0; j < 4; j++) {
            __half2 t = __hmul2(q0.h2[j], wv0);
            t = __hfma2(q2.h2[j], wv1, t);
            t = __hfma2(q4.h2[j], wv2, t);
            t = __hfma2(q6.h2[j], wv3, t);
            fA0.h2[j] = t;
            __half2 s = __hmul2(q1.h2[j], wv0);
            s = __hfma2(q3.h2[j], wv1, s);
            s = __hfma2(q5.h2[j], wv2, s);
            s = __hfma2(q7.h2[j], wv3, s);
            fA1.h2[j] = s;
        }

        // --- 8 MFMA: D[p][o] += V(16x32) * W^T(32x16) per o-tile ---
        __builtin_amdgcn_s_setprio(1);
#pragma unroll
        for (int nf = 0; nf < 4; nf++) {
            acc[nf] = __builtin_amdgcn_mfma_f32_16x16x32_f16(fA0.v, wB[nf * 2],     acc[nf], 0, 0, 0);
            acc[nf] = __builtin_amdgcn_mfma_f32_16x16x32_f16(fA1.v, wB[nf * 2 + 1], acc[nf], 0, 0, 0);
        }
        __builtin_amdgcn_s_setprio(0);
    }

    // epilogue: D map row=(l>>4)*4+rr = pixel-in-wave, col=l&15 = o-in-tile
#pragma unroll
    for (int nf = 0; nf < 4; nf++) {
        int o = nf * 16 + p_loc;
        float bo = bias[o];
        int wo = wobase + chunk * 4;
        float* op = out + (((size_t)n * COUT + o) * HH + ho_w) * WW + wo;
#pragma unroll
        for (int rr = 0; rr < 4; rr++) {
            float v = acc[nf][rr] + bo;
            op[rr] = fmaxf(v, 0.f);
        }
    }
}

// ---------------------------------------------------------------------------
extern "C" void kernel_launch(void* const* d_in, const int* in_sizes, int n_in,
                              void* d_out, int out_size, void* d_ws, size_t ws_size,
                              hipStream_t stream) {
    const float* x     = (const float*)d_in[0];
    const float* w_off = (const float*)d_in[1];
    const float* b_off = (const float*)d_in[2];
    const float* w_mod = (const float*)d_in[3];
    const float* b_mod = (const float*)d_in[4];
    const float* w     = (const float*)d_in[5];
    const float* b     = (const float*)d_in[6];
    float* out = (float*)d_out;

    // ws layout: wfrag f16[36864] | wauxf f16[18432] | baux f32[32] |
    //            xt f16 NHWC [4*HW*64]                       (~19 MB)
    unsigned short* wfrag = (unsigned short*)d_ws;
    unsigned short* wauxf = wfrag + 36864;
    float* baux = (float*)(wauxf + 18432);
    unsigned short* xt = (unsigned short*)(baux + 32);

    to_nhwc<<<dim3(144, NB), dim3(256), 0, stream>>>(x, xt);
    prep_weights<<<dim3(144), dim3(256), 0, stream>>>(w, w_off, w_mod, b_off,
                                                      b_mod, wfrag, wauxf, baux);
    dcn_fused<<<dim3(2304), dim3(256), 0, stream>>>(xt, wfrag, wauxf, baux, b, out);
}

// Round 13
// 70.702 us; speedup vs baseline: 1.9043x; 1.9043x over previous
//
#include <hip/hip_runtime.h>
#include <hip/hip_bf16.h>
#include <hip/hip_fp16.h>
#include <math.h>

// DCNv2 forward, fully fused, f16 pipeline: per block stage a 6x36-pixel NHWC
// f16 window in LDS (XOR-swizzled, 128 B/pixel); aux conv (f16 MFMA) reads
// taps from it -> oml (pixel-major f16) in LDS; each lane preloads its
// pixel's 27 oml values into registers; the 9-tap main loop is FULLY UNROLLED
// (register-resident geometry, LDS-read-only) so the scheduler pipelines
// corner ds_reads/weight loads across taps. Bilinear runs on packed f16
// (v_pk_fma_f16) straight into MFMA A-fragments (D = V*W^T); rare exec-masked
// global fallback for large offsets. Tile = 2 rows x 32 cols (out lines are
// full 128-B lines per block — r12 lesson), 4 waves, ~31 KB LDS.
// x [4,64,192,192] f32; w_off [18,64,3,3]; b_off[18]; w_mod [9,64,3,3]; b_mod[9];
// w [64,64,3,3]; b[64]; out [4,64,192,192] f32.

#define NB   4
#define CIN  64
#define COUT 64
#define HH   192
#define WW   192
#define HW   (HH*WW)

typedef __attribute__((ext_vector_type(4))) float f32x4;
typedef __attribute__((ext_vector_type(8))) _Float16 f16x8;
typedef __attribute__((ext_vector_type(4))) unsigned int u32x4;

__device__ __forceinline__ int iclamp(int v, int lo, int hi) {
    return v < lo ? lo : (v > hi ? hi : v);
}
__device__ __forceinline__ unsigned short f16bits(float f) {
    __half h = __float2half(f);
    union { __half h; unsigned short u; } t; t.h = h; return t.u;
}
__device__ __forceinline__ float h2f(unsigned short u) {
    union { unsigned short u; __half h; } t; t.u = u; return __half2float(t.h);
}

// ---------------------------------------------------------------------------
// Kernel A: x f32 NCHW -> xt f16 NHWC (128 B per pixel).
// ---------------------------------------------------------------------------
__global__ __launch_bounds__(256) void to_nhwc(
        const float* __restrict__ x, unsigned short* __restrict__ xt) {
    int n  = blockIdx.y;
    int px = blockIdx.x * 256 + threadIdx.x;     // 0..HW-1
    const float* xn = x + (size_t)n * CIN * HW + px;
    union { unsigned short us[64]; u32x4 q[8]; } pk;
#pragma unroll
    for (int c = 0; c < 64; c++) pk.us[c] = f16bits(xn[c * HW]);
    u32x4* dst = (u32x4*)(xt + ((size_t)n * HW + px) * 64);
#pragma unroll
    for (int i = 0; i < 8; i++) dst[i] = pk.q[i];
}

// ---------------------------------------------------------------------------
// Kernel 0: weight repack into MFMA fragment order (f16 bits).
//  wfrag (main): idx = (((k*4+nf)*2+kc)*64 + l)*8 + j
//        holds W[o = nf*16 + (l&15)][c = kc*32 + (l>>4)*8 + j]
//  wauxf (aux, 32 out-ch padded from 27): idx = ((k*4 + ga*2 + kc)*64 + l)*8 + j
//  baux  f32[32]: b_off | b_mod | 0
// ---------------------------------------------------------------------------
__global__ __launch_bounds__(256) void prep_weights(
        const float* __restrict__ w, const float* __restrict__ w_off,
        const float* __restrict__ w_mod, const float* __restrict__ b_off,
        const float* __restrict__ b_mod, unsigned short* __restrict__ wfrag,
        unsigned short* __restrict__ wauxf, float* __restrict__ baux) {
    int idx = blockIdx.x * 256 + threadIdx.x;
    if (idx < 36864) {
        int j    = idx & 7;
        int lane = (idx >> 3) & 63;
        int kc   = (idx >> 9) & 1;
        int g    = (idx >> 10) & 3;
        int k    = idx >> 12;
        int o = g * 16 + (lane & 15);
        int c = kc * 32 + (lane >> 4) * 8 + j;
        wfrag[idx] = f16bits(w[(o * 64 + c) * 9 + k]);
    }
    if (idx < 18432) {
        int j    = idx & 7;
        int lane = (idx >> 3) & 63;
        int kc   = (idx >> 9) & 1;
        int ga   = (idx >> 10) & 1;
        int k    = idx >> 11;
        int o = ga * 16 + (lane & 15);
        int c = kc * 32 + (lane >> 4) * 8 + j;
        float v = 0.f;
        if (o < 18)      v = w_off[(o * 64 + c) * 9 + k];
        else if (o < 27) v = w_mod[((o - 18) * 64 + c) * 9 + k];
        wauxf[idx] = f16bits(v);
    }
    if (idx < 32) {
        float v = 0.f;
        if (idx < 18)      v = b_off[idx];
        else if (idx < 27) v = b_mod[idx - 18];
        baux[idx] = v;
    }
}

// ---------------------------------------------------------------------------
// Fused kernel. Tile = 2 output rows x 32 cols. 4 waves: wave = (r2<<1)|g2.
// Window: 6 rows x 36 cols (rows ho2-2..ho2+3, cols wobase-2..wobase+33),
// 128 B/slot, XOR-swizzled (byte ^ (slot&7)<<4). LDS = 27648 + 4096 B.
// ---------------------------------------------------------------------------
__global__ __launch_bounds__(256, 4) void dcn_fused(
        const unsigned short* __restrict__ xt,
        const unsigned short* __restrict__ wfrag,
        const unsigned short* __restrict__ wauxf,
        const float* __restrict__ baux,
        const float* __restrict__ bias,
        float* __restrict__ out) {
    __shared__ __align__(16) unsigned short win[216 * 64];  // 27648 B
    __shared__ __align__(16) unsigned short oml[2][32][32]; // 4096 B, pixel-major

    int tid = threadIdx.x;
    int l   = tid & 63;
    int wv  = __builtin_amdgcn_readfirstlane(tid >> 6);   // 0..3
    int r2  = wv >> 1;        // output row within tile
    int g2  = wv & 1;         // 16-px half within row

    int id = blockIdx.x;                        // 0..2303
    int sw = (id & 7) * 288 + (id >> 3);        // bijective XCD swizzle
    int n  = sw / 576;
    int r  = sw % 576;
    int ho2    = (r / 6) * 2;
    int wobase = (r % 6) * 32;

    const char* xb = (const char*)xt + (size_t)n * HW * 128;

    // ---------------- stage the 6x36 window into LDS (swizzled) ----------
    if (tid < 216) {
        int rw = tid / 36, cl = tid - rw * 36;
        int gy = iclamp(ho2 - 2 + rw, 0, HH - 1);
        int gx = iclamp(wobase - 2 + cl, 0, WW - 1);
        const u32x4* src = (const u32x4*)(xb + ((size_t)gy * WW + gx) * 128);
        char* dst = (char*)win + tid * 128;
        int xw = (tid & 7) << 4;
#pragma unroll
        for (int c = 0; c < 8; c++)
            *(u32x4*)(dst + ((c * 16) ^ xw)) = src[c];
    }
    __syncthreads();

    // ================= Phase A: aux conv for this tile =================
    {
        f32x4 aacc[2];
        aacc[0] = (f32x4){0.f, 0.f, 0.f, 0.f};
        aacc[1] = (f32x4){0.f, 0.f, 0.f, 0.f};
        const f16x8 zero8 = (f16x8){0, 0, 0, 0, 0, 0, 0, 0};
        int pa   = g2 * 16 + (l & 15);          // px in row, 0..31
        int cba  = (l >> 4) * 16;               // 8-ch chunk byte offset
        int ho_w = ho2 + r2;

#pragma unroll 1
        for (int k = 0; k < 9; k++) {
            int ky = k / 3, kx = k - 3 * (k / 3);
            int ys = ho_w + ky - 1;
            if ((unsigned)ys >= (unsigned)HH) continue;   // uniform row skip
            int xs = wobase + pa + kx - 1;
            bool ok = (unsigned)xs < (unsigned)WW;
            int sA = (ky + 1 + r2) * 36 + (pa + kx + 1);  // window slot
            const char* pp = (const char*)win + sA * 128;
            int xw = (sA & 7) << 4;
            const f16x8* wa = ((const f16x8*)wauxf) + (k * 4) * 64 + l;
#pragma unroll
            for (int kc = 0; kc < 2; kc++) {
                f16x8 bv = *(const f16x8*)(pp + ((kc * 64 + cba) ^ xw));
                if (!ok) bv = zero8;
                f16x8 a0 = wa[(kc)     * 64];      // o 0..15
                f16x8 a1 = wa[(2 + kc) * 64];      // o 16..31
                aacc[0] = __builtin_amdgcn_mfma_f32_16x16x32_f16(a0, bv, aacc[0], 0, 0, 0);
                aacc[1] = __builtin_amdgcn_mfma_f32_16x16x32_f16(a1, bv, aacc[1], 0, 0, 0);
            }
        }
#pragma unroll
        for (int h = 0; h < 2; h++) {
#pragma unroll
            for (int rr = 0; rr < 4; rr++) {
                int o = h * 16 + (l >> 4) * 4 + rr;
                float v = aacc[h][rr] + baux[o];
                if (o >= 18) v = 2.f / (1.f + expf(-v));
                oml[r2][pa][o] = f16bits(v);      // pixel-major
            }
        }
    }
    __syncthreads();   // window + oml ready; no further barriers

    // ================= Phase B: deform sample + main conv =================
    f32x4 acc[4];
#pragma unroll
    for (int nf = 0; nf < 4; nf++) acc[nf] = (f32x4){0.f, 0.f, 0.f, 0.f};

    int p_loc = l & 15;             // pixel within wave's 16 (M-row)
    int chunk = l >> 4;             // K-chunk 0..3
    int p     = g2 * 16 + p_loc;    // pixel in row, 0..31
    int ho_w  = ho2 + r2;
    int wox   = wobase + p;         // global wo of this pixel
    int cb0   = chunk * 16;         // chunk byte offset within pixel line

    // preload this pixel's 27 oml values into registers (4 x b128)
    union { u32x4 q[4]; unsigned short us[32]; } om;
    {
        const u32x4* omp = (const u32x4*)&oml[r2][p][0];
        om.q[0] = omp[0]; om.q[1] = omp[1];
        om.q[2] = omp[2]; om.q[3] = omp[3];
    }

    union Q { u32x4 u; __half2 h2[4]; };

#pragma unroll
    for (int k = 0; k < 9; k++) {
        // weight B-fragments (L1-broadcast across waves)
        const f16x8* wfk = ((const f16x8*)wfrag) + (k * 8) * 64 + l;
        f16x8 wB[8];
#pragma unroll
        for (int f = 0; f < 8; f++) wB[f] = wfk[f * 64];

        // --- geometry (register-only; no LDS on this chain) ---
        int ky = k / 3, kx = k - 3 * (k / 3);
        float offy = h2f(om.us[2 * k]);
        float offx = h2f(om.us[2 * k + 1]);
        float mm   = h2f(om.us[18 + k]);
        float py  = offy + (float)(ho_w - 1 + ky);
        float pxf = offx + (float)(wox - 1 + kx);
        float y0f = floorf(py), x0f = floorf(pxf);
        float ly = py - y0f, lx = pxf - x0f;
        int y0 = (int)y0f, x0 = (int)x0f;
        int y1 = y0 + 1, x1 = x0 + 1;
        bool y0ok = (unsigned)y0 < (unsigned)HH, y1ok = (unsigned)y1 < (unsigned)HH;
        bool x0ok = (unsigned)x0 < (unsigned)WW, x1ok = (unsigned)x1 < (unsigned)WW;
        float wt0 = (y0ok && x0ok) ? mm * (1.f - ly) * (1.f - lx) : 0.f;
        float wt1 = (y0ok && x1ok) ? mm * (1.f - ly) * lx         : 0.f;
        float wt2 = (y1ok && x0ok) ? mm * ly * (1.f - lx)         : 0.f;
        float wt3 = (y1ok && x1ok) ? mm * ly * lx                 : 0.f;
        int y0c = iclamp(y0, 0, HH - 1), y1c = iclamp(y1, 0, HH - 1);
        int x0c = iclamp(x0, 0, WW - 1), x1c = iclamp(x1, 0, WW - 1);

        // --- window slots ---
        int sy0 = y0c - ho2 + 2,    sy1 = y1c - ho2 + 2;     // want 0..5
        int sx0 = x0c - wobase + 2, sx1 = x1c - wobase + 2;  // want 0..35
        int sy0c = iclamp(sy0, 0, 5),  sy1c = iclamp(sy1, 0, 5);
        int sx0c = iclamp(sx0, 0, 35), sx1c = iclamp(sx1, 0, 35);
        bool fb00 = (wt0 > 0.f) && ((sy0 != sy0c) | (sx0 != sx0c));
        bool fb01 = (wt1 > 0.f) && ((sy0 != sy0c) | (sx1 != sx1c));
        bool fb10 = (wt2 > 0.f) && ((sy1 != sy1c) | (sx0 != sx0c));
        bool fb11 = (wt3 > 0.f) && ((sy1 != sy1c) | (sx1 != sx1c));

        int s00 = sy0c * 36 + sx0c, s01 = sy0c * 36 + sx1c;
        int s10 = sy1c * 36 + sx0c, s11 = sy1c * 36 + sx1c;
        const char* w00 = (const char*)win + s00 * 128;
        const char* w01 = (const char*)win + s01 * 128;
        const char* w10 = (const char*)win + s10 * 128;
        const char* w11 = (const char*)win + s11 * 128;
        int x00 = (s00 & 7) << 4, x01 = (s01 & 7) << 4;
        int x10 = (s10 & 7) << 4, x11 = (s11 & 7) << 4;
        Q q0, q1, q2, q3, q4, q5, q6, q7;
        q0.u = *(const u32x4*)(w00 + ((cb0)      ^ x00));
        q1.u = *(const u32x4*)(w00 + ((cb0 + 64) ^ x00));
        q2.u = *(const u32x4*)(w01 + ((cb0)      ^ x01));
        q3.u = *(const u32x4*)(w01 + ((cb0 + 64) ^ x01));
        q4.u = *(const u32x4*)(w10 + ((cb0)      ^ x10));
        q5.u = *(const u32x4*)(w10 + ((cb0 + 64) ^ x10));
        q6.u = *(const u32x4*)(w11 + ((cb0)      ^ x11));
        q7.u = *(const u32x4*)(w11 + ((cb0 + 64) ^ x11));

        // --- rare fallback: nonzero-weight corner outside window ---
        if (__builtin_expect(fb00 | fb01 | fb10 | fb11, 0)) {
            if (fb00) { const char* gp = xb + ((size_t)y0c * WW + x0c) * 128 + cb0;
                        q0.u = *(const u32x4*)gp; q1.u = *(const u32x4*)(gp + 64); }
            if (fb01) { const char* gp = xb + ((size_t)y0c * WW + x1c) * 128 + cb0;
                        q2.u = *(const u32x4*)gp; q3.u = *(const u32x4*)(gp + 64); }
            if (fb10) { const char* gp = xb + ((size_t)y1c * WW + x0c) * 128 + cb0;
                        q4.u = *(const u32x4*)gp; q5.u = *(const u32x4*)(gp + 64); }
            if (fb11) { const char* gp = xb + ((size_t)y1c * WW + x1c) * 128 + cb0;
                        q6.u = *(const u32x4*)gp; q7.u = *(const u32x4*)(gp + 64); }
        }

        // --- packed f16 bilinear -> A-fragments (v_pk_fma_f16, no repack) ---
        __half2 wv0 = __float2half2_rn(wt0);
        __half2 wv1 = __float2half2_rn(wt1);
        __half2 wv2 = __float2half2_rn(wt2);
        __half2 wv3 = __float2half2_rn(wt3);
        union { __half2 h2[4]; f16x8 v; } fA0, fA1;
#pragma unroll
        for (int j = 0; j < 4; j++) {
            __half2 t = __hmul2(q0.h2[j], wv0);
            t = __hfma2(q2.h2[j], wv1, t);
            t = __hfma2(q4.h2[j], wv2, t);
            t = __hfma2(q6.h2[j], wv3, t);
            fA0.h2[j] = t;
            __half2 s = __hmul2(q1.h2[j], wv0);
            s = __hfma2(q3.h2[j], wv1, s);
            s = __hfma2(q5.h2[j], wv2, s);
            s = __hfma2(q7.h2[j], wv3, s);
            fA1.h2[j] = s;
        }

        // --- 8 MFMA: D[p][o] += V(16x32) * W^T(32x16) per o-tile ---
#pragma unroll
        for (int nf = 0; nf < 4; nf++) {
            acc[nf] = __builtin_amdgcn_mfma_f32_16x16x32_f16(fA0.v, wB[nf * 2],     acc[nf], 0, 0, 0);
            acc[nf] = __builtin_amdgcn_mfma_f32_16x16x32_f16(fA1.v, wB[nf * 2 + 1], acc[nf], 0, 0, 0);
        }
    }

    // epilogue: D map row=(l>>4)*4+rr = pixel-in-wave, col=l&15 = o-in-tile
    // out lines: 16 cols x 4 B x (chunk,rr) = full 128-B lines per block.
#pragma unroll
    for (int nf = 0; nf < 4; nf++) {
        int o = nf * 16 + p_loc;
        float bo = bias[o];
        int wo = wobase + g2 * 16 + chunk * 4;
        float* op = out + (((size_t)n * COUT + o) * HH + ho_w) * WW + wo;
#pragma unroll
        for (int rr = 0; rr < 4; rr++) {
            float v = acc[nf][rr] + bo;
            op[rr] = fmaxf(v, 0.f);
        }
    }
}

// ---------------------------------------------------------------------------
extern "C" void kernel_launch(void* const* d_in, const int* in_sizes, int n_in,
                              void* d_out, int out_size, void* d_ws, size_t ws_size,
                              hipStream_t stream) {
    const float* x     = (const float*)d_in[0];
    const float* w_off = (const float*)d_in[1];
    const float* b_off = (const float*)d_in[2];
    const float* w_mod = (const float*)d_in[3];
    const float* b_mod = (const float*)d_in[4];
    const float* w     = (const float*)d_in[5];
    const float* b     = (const float*)d_in[6];
    float* out = (float*)d_out;

    // ws layout: wfrag f16[36864] | wauxf f16[18432] | baux f32[32] |
    //            xt f16 NHWC [4*HW*64]                       (~19 MB)
    unsigned short* wfrag = (unsigned short*)d_ws;
    unsigned short* wauxf = wfrag + 36864;
    float* baux = (float*)(wauxf + 18432);
    unsigned short* xt = (unsigned short*)(baux + 32);

    to_nhwc<<<dim3(144, NB), dim3(256), 0, stream>>>(x, xt);
    prep_weights<<<dim3(144), dim3(256), 0, stream>>>(w, w_off, w_mod, b_off,
                                                      b_mod, wfrag, wauxf, baux);
    dcn_fused<<<dim3(2304), dim3(256), 0, stream>>>(xt, wfrag, wauxf, baux, b, out);
}